// Round 6
// baseline (436.266 us; speedup 1.0000x reference)
//
#include <hip/hip_runtime.h>

// Problem constants
constexpr int B_ = 8, H_ = 64, W_ = 64, C0 = 16, D_ = 128, K_ = 8192;
constexpr int N_ = B_ * H_ * W_;  // 32768 pixels

typedef __attribute__((ext_vector_type(8))) short short8;  // 8 bf16
typedef __attribute__((ext_vector_type(4))) float f32x4;   // MFMA C/D

__device__ __forceinline__ float gelu_f(float x) {
    return 0.5f * x * (1.0f + erff(x * 0.70710678118654752440f));
}

__device__ __forceinline__ unsigned short f2bf(float f) {  // RNE f32->bf16
    unsigned u = __float_as_uint(f);
    u += 0x7fffu + ((u >> 16) & 1u);
    return (unsigned short)(u >> 16);
}

// ---------------------------------------------------------------------------
// One fused prep kernel (block-range switched):
//  A [0,2048):      x NCHW f32 -> xtbf NHWC bf16
//  B [2048,2624):   ew2 OIHW -> wtbf2 [t][co][ci] bf16
//  C [2624,3200):   dw1 OIHW -> wtbf3 [t][co][ci] bf16
//  D [3200,3232):   e2[k] = ||embed_k||^2 (fp32)
//  E [3232,4256):   embed f32 -> embbf bf16
//  F [4256,4336):   ew1 OIHW -> wtb1b [co][kk=t*16+ci, pad 160] bf16
//  G [4336,4464):   partial[n] = 0 (VQ cross-block atomic-merge slots)
__global__ __launch_bounds__(256) void prep_kernel(
    const float* __restrict__ x, const float* __restrict__ ew1,
    const float* __restrict__ ew2, const float* __restrict__ dw1,
    const float* __restrict__ embed, unsigned short* __restrict__ xtbf,
    unsigned short* __restrict__ wtbf2, unsigned short* __restrict__ wtbf3,
    float* __restrict__ e2, unsigned short* __restrict__ embbf,
    unsigned short* __restrict__ wtb1b,
    unsigned long long* __restrict__ partial) {
    int blk = blockIdx.x;
    int tid = threadIdx.x;
    if (blk < 2048) {  // A: xtbf (out-contiguous)
        int j = blk * 256 + tid;
        int c = j & 15, w = (j >> 4) & 63, h = (j >> 10) & 63, b = j >> 16;
        xtbf[j] = f2bf(x[(((b << 4) + c) << 12) + (h << 6) + w]);
    } else if (blk < 3200) {  // B/C: 3x3 128-ch weights -> [t][co][ci] bf16
        const float* src = (blk < 2624) ? ew2 : dw1;
        unsigned short* dst = (blk < 2624) ? wtbf2 : wtbf3;
        int i = (blk - ((blk < 2624) ? 2048 : 2624)) * 256 + tid;
        int ci = i & 127, co = (i >> 7) & 127, t = i >> 14;
        dst[i] = f2bf(src[(co * 128 + ci) * 9 + t]);
    } else if (blk < 3232) {  // D: e2
        int k = (blk - 3200) * 256 + tid;
        const float4* e4 = (const float4*)(embed + (size_t)k * 128);
        float s = 0.0f;
#pragma unroll 8
        for (int i = 0; i < 32; ++i) {
            float4 v = e4[i];
            s += v.x * v.x + v.y * v.y + v.z * v.z + v.w * v.w;
        }
        e2[k] = s;
    } else if (blk < 4256) {  // E: embbf
        int i = (blk - 3232) * 256 + tid;
        float4 v = ((const float4*)embed)[i];
        uint2 o;
        o.x = (unsigned)f2bf(v.x) | ((unsigned)f2bf(v.y) << 16);
        o.y = (unsigned)f2bf(v.z) | ((unsigned)f2bf(v.w) << 16);
        ((uint2*)embbf)[i] = o;
    } else if (blk < 4336) {  // F: wtb1b [128 co][160 kk]
        int i = (blk - 4256) * 256 + tid;  // < 20480
        int co = i / 160, kk = i % 160;
        float v = 0.0f;
        if (kk < 144) {
            int t = kk >> 4, ci = kk & 15;
            v = ew1[(co * 16 + ci) * 9 + t];
        }
        wtb1b[i] = f2bf(v);
    } else {  // G: zero the VQ merge slots (poisoned 0xAA by harness)
        int i = (blk - 4336) * 256 + tid;  // < 32768
        partial[i] = 0ULL;
    }
}

// ---------------------------------------------------------------------------
// conv1: 16->128 3x3 + GELU via MFMA, K=160 (9 taps x 16 ci, zero-padded).
__global__ __launch_bounds__(256, 2) void conv1_mfma_kernel(
    const unsigned short* __restrict__ xtbf,   // NHWC [B,64,64,16] bf16
    const unsigned short* __restrict__ wtb1b,  // [128][160] bf16
    const float* __restrict__ bias,            // [128]
    unsigned short* __restrict__ out) {        // NHWC [B,64,64,128] bf16
    constexpr int LDA = 168;
    __shared__ __align__(16) unsigned short As[64 * LDA];  // 21504 B
    int tid = threadIdx.x;
    int wv = tid >> 6, lane = tid & 63;
    int r = lane & 15, q = lane >> 4;
    int h0 = blockIdx.x & 63, b = blockIdx.x >> 6;

#pragma unroll
    for (int j = 0; j < 5; ++j) {
        int s = tid + j * 256;
        if (s < 1152) {
            int px = s / 18, rem = s % 18;
            int t = rem >> 1, half = rem & 1;
            int hh = h0 + t / 3 - 1, ww = px + t % 3 - 1;
            float4 v = make_float4(0.f, 0.f, 0.f, 0.f);
            if ((unsigned)hh < 64u && (unsigned)ww < 64u)
                v = *(const float4*)(xtbf + (((b * 64 + hh) * 64 + ww) << 4) +
                                     half * 8);
            *(float4*)(As + px * LDA + t * 16 + half * 8) = v;
        } else {
            int z = s - 1152;  // < 128
            int px = z >> 1, half = z & 1;
            *(float4*)(As + px * LDA + 144 + half * 8) =
                make_float4(0.f, 0.f, 0.f, 0.f);
        }
    }
    __syncthreads();

    f32x4 acc[4][2];
#pragma unroll
    for (int ms = 0; ms < 4; ++ms)
#pragma unroll
        for (int ns = 0; ns < 2; ++ns) acc[ms][ns] = (f32x4){0.f, 0.f, 0.f, 0.f};

#pragma unroll
    for (int k = 0; k < 5; ++k) {
        short8 af[4], bf[2];
#pragma unroll
        for (int ms = 0; ms < 4; ++ms)
            af[ms] = *(const short8*)(As + (ms * 16 + r) * LDA + k * 32 + q * 8);
#pragma unroll
        for (int ns = 0; ns < 2; ++ns) {
            int co = wv * 32 + ns * 16 + r;
            bf[ns] = *(const short8*)(wtb1b + co * 160 + k * 32 + q * 8);
        }
#pragma unroll
        for (int ms = 0; ms < 4; ++ms)
#pragma unroll
            for (int ns = 0; ns < 2; ++ns)
                acc[ms][ns] = __builtin_amdgcn_mfma_f32_16x16x32_bf16(
                    af[ms], bf[ns], acc[ms][ns], 0, 0, 0);
    }

#pragma unroll
    for (int ns = 0; ns < 2; ++ns) {
        int co = wv * 32 + ns * 16 + r;
        float bv = bias[co];
#pragma unroll
        for (int ms = 0; ms < 4; ++ms)
#pragma unroll
            for (int rg = 0; rg < 4; ++rg) {
                int px = ms * 16 + q * 4 + rg;
                int pix = (b * 64 + h0) * 64 + px;
                out[(size_t)pix * 128 + co] = f2bf(gelu_f(acc[ms][ns][rg] + bv));
            }
    }
}

// ---------------------------------------------------------------------------
// 3x3 128->128 conv + GELU via MFMA; halo staged once, weights from L2.
template <bool OUT_BF16>
__global__ __launch_bounds__(256, 2) void conv3x3_mfma_kernel(
    const unsigned short* __restrict__ in,   // NHWC [B,64,64,128] bf16
    const unsigned short* __restrict__ wtb,  // [9][co][ci] bf16
    const float* __restrict__ bias,          // [128]
    void* __restrict__ out_) {               // NHWC fp32 or bf16
    constexpr int LDC = 136;
    __shared__ __align__(16) unsigned short As[3 * 66 * LDC];  // 53856 B
    int tid = threadIdx.x;
    int wv = tid >> 6, lane = tid & 63;
    int r = lane & 15, q = lane >> 4;
    int h0 = blockIdx.x & 63, b = blockIdx.x >> 6;

    for (int j = 0; j < 13; ++j) {
        int s = tid + j * 256;
        if (s < 3168) {
            int col = s >> 4, chunk = s & 15;
            int ry = col / 66, cx = col % 66;
            int hh = h0 - 1 + ry, ww = cx - 1;
            float4 v = make_float4(0.f, 0.f, 0.f, 0.f);
            if ((unsigned)hh < 64u && (unsigned)ww < 64u)
                v = *(const float4*)(in + ((size_t)((b * 64 + hh) * 64 + ww))
                                              * 128 + chunk * 8);
            *(float4*)(As + col * LDC + chunk * 8) = v;
        }
    }
    __syncthreads();

    f32x4 acc[4][2];
#pragma unroll
    for (int ms = 0; ms < 4; ++ms)
#pragma unroll
        for (int ns = 0; ns < 2; ++ns) acc[ms][ns] = (f32x4){0.f, 0.f, 0.f, 0.f};

    for (int t = 0; t < 9; ++t) {
        int dy = t / 3, dx = t % 3;
        const unsigned short* wsrc = wtb + t * 16384;
#pragma unroll
        for (int k = 0; k < 4; ++k) {
            short8 af[4], bf[2];
#pragma unroll
            for (int ms = 0; ms < 4; ++ms) {
                int col = dy * 66 + ms * 16 + r + dx;
                af[ms] = *(const short8*)(As + col * LDC + k * 32 + q * 8);
            }
#pragma unroll
            for (int ns = 0; ns < 2; ++ns) {
                int co = wv * 32 + ns * 16 + r;
                bf[ns] = *(const short8*)(wsrc + co * 128 + k * 32 + q * 8);
            }
#pragma unroll
            for (int ms = 0; ms < 4; ++ms)
#pragma unroll
                for (int ns = 0; ns < 2; ++ns)
                    acc[ms][ns] = __builtin_amdgcn_mfma_f32_16x16x32_bf16(
                        af[ms], bf[ns], acc[ms][ns], 0, 0, 0);
        }
    }

#pragma unroll
    for (int ns = 0; ns < 2; ++ns) {
        int co = wv * 32 + ns * 16 + r;
        float bv = bias[co];
#pragma unroll
        for (int ms = 0; ms < 4; ++ms)
#pragma unroll
            for (int rg = 0; rg < 4; ++rg) {
                int px = ms * 16 + q * 4 + rg;
                int pix = (b * 64 + h0) * 64 + px;
                float g = gelu_f(acc[ms][ns][rg] + bv);
                if (OUT_BF16)
                    ((unsigned short*)out_)[(size_t)pix * 128 + co] = f2bf(g);
                else
                    ((float*)out_)[(size_t)pix * 128 + co] = g;
            }
    }
}

// ---------------------------------------------------------------------------
// VQ argmin via bf16 MFMA, K-split x2 for occupancy (R5 post-mortem: latency-
// bound at 2 waves/SIMD). 1024 blocks: blockIdx&1 = codebook half (4096
// codes, 16 iters), blockIdx>>1 = pixel group. 4 blocks/CU (launch_bounds
// (256,4); VGPR 88, LDS 33 KB both allow it) -> 4 waves/SIMD cover the ~200
// cyc L2 load latency with other waves' MFMA.
// acc init = -e2/2 -> score = f.e - e2/2, argMAX. Low 7 mantissa bits carry
// key (larger key = smaller code) -> single v_max_f32 running argmax.
// Cross-block merge: atomicMax on packed (sortable_score<<32 | (8191-code)).
__global__ __launch_bounds__(256, 4) void vq_mfma_kernel(
    const unsigned short* __restrict__ flatbf,  // [N][128] bf16
    const unsigned short* __restrict__ embbf,   // [K][128] bf16
    const float* __restrict__ e2,               // [K] fp32
    unsigned long long* __restrict__ partial) { // [N] packed, zero-inited
    constexpr int LDA = 136;
    __shared__ __align__(16) unsigned short SH[16640];  // 33280 B (stage+merge)
    int tid = threadIdx.x;
    int wv = tid >> 6, lane = tid & 63;
    int r = lane & 15, q = lane >> 4;
    int half = blockIdx.x & 1;
    int m0 = (blockIdx.x >> 1) * 64;
    int kbase = half * 4096;

    // stage A (64 px x 128 d) and preload frags to registers
#pragma unroll
    for (int j = 0; j < 4; ++j) {
        int row = j * 16 + (tid >> 4), col = tid & 15;
        float4 v = *(const float4*)(flatbf + (size_t)(m0 + row) * 128 + col * 8);
        *(float4*)(SH + row * LDA + col * 8) = v;
    }
    __syncthreads();
    short8 afr[4][4];  // [ms][k]
#pragma unroll
    for (int ms = 0; ms < 4; ++ms)
#pragma unroll
        for (int k = 0; k < 4; ++k)
            afr[ms][k] = *(const short8*)(SH + (ms * 16 + r) * LDA + k * 32 + q * 8);
    __syncthreads();  // all waves done reading A; SH reusable for merge

    float best[4][4];
#pragma unroll
    for (int ms = 0; ms < 4; ++ms)
#pragma unroll
        for (int rg = 0; rg < 4; ++rg) best[ms][rg] = -3.4e38f;

    const unsigned short* bp = embbf + (size_t)(kbase + wv * 64 + r) * 128 + q * 8;
    const float* e2p = e2 + kbase + wv * 64 + r;

    for (int it = 0; it < 16; ++it) {
        float e2v[4];
#pragma unroll
        for (int ns = 0; ns < 4; ++ns) e2v[ns] = e2p[it * 256 + ns * 16];

        f32x4 acc[4][4];  // [ms][ns], init -e2/2
#pragma unroll
        for (int ns = 0; ns < 4; ++ns) {
            float v = -0.5f * e2v[ns];
#pragma unroll
            for (int ms = 0; ms < 4; ++ms) acc[ms][ns] = (f32x4){v, v, v, v};
        }

#pragma unroll
        for (int k = 0; k < 4; ++k) {
            short8 bfr[4];
#pragma unroll
            for (int ns = 0; ns < 4; ++ns)
                bfr[ns] = *(const short8*)(bp + (size_t)it * 32768 + ns * 2048 +
                                           k * 32);
#pragma unroll
            for (int ms = 0; ms < 4; ++ms)
#pragma unroll
                for (int ns = 0; ns < 4; ++ns)
                    acc[ms][ns] = __builtin_amdgcn_mfma_f32_16x16x32_bf16(
                        afr[ms][k], bfr[ns], acc[ms][ns], 0, 0, 0);
        }

#pragma unroll
        for (int ns = 0; ns < 4; ++ns) {
            unsigned key = 127u - (unsigned)(it * 4 + ns);
#pragma unroll
            for (int ms = 0; ms < 4; ++ms)
#pragma unroll
                for (int rg = 0; rg < 4; ++rg) {
                    unsigned u = (__float_as_uint(acc[ms][ns][rg]) & 0xFFFFFF80u)
                                 | key;
                    best[ms][rg] = fmaxf(best[ms][rg], __uint_as_float(u));
                }
        }
    }

    // in-block merge of 64 candidates/pixel via LDS
    float* sred = (float*)SH;      // [64][65] floats
    int* ired = (int*)SH + 4160;   // [64][65] ints
    int cand = wv * 16 + r;
#pragma unroll
    for (int ms = 0; ms < 4; ++ms)
#pragma unroll
        for (int rg = 0; rg < 4; ++rg) {
            unsigned bits = __float_as_uint(best[ms][rg]);
            unsigned keyinv = 127u - (bits & 127u);
            int code = kbase + (int)(keyinv >> 2) * 256 + wv * 64 +
                       (int)(keyinv & 3u) * 16 + r;
            int pixel = ms * 16 + q * 4 + rg;
            sred[pixel * 65 + cand] = best[ms][rg];
            ired[pixel * 65 + cand] = code;
        }
    __syncthreads();
    if (tid < 64) {
        float bs = sred[tid * 65];
        int bi = ired[tid * 65];
        for (int c = 1; c < 64; ++c) {
            float s = sred[tid * 65 + c];
            int i2 = ired[tid * 65 + c];
            if (s > bs || (s == bs && i2 < bi)) {
                bs = s;
                bi = i2;
            }
        }
        // cross-block merge: monotone float->uint, larger = better score;
        // low field (8191-code) makes ties pick the smaller code.
        unsigned sb = __float_as_uint(bs);
        sb = (sb & 0x80000000u) ? ~sb : (sb | 0x80000000u);
        unsigned long long packed =
            ((unsigned long long)sb << 32) | (unsigned)(8191 - bi);
        atomicMax(partial + m0 + tid, packed);
    }
}

// ---------------------------------------------------------------------------
__global__ __launch_bounds__(256) void gather_bf16_kernel(
    const unsigned short* __restrict__ embbf,
    const unsigned long long* __restrict__ partial,
    unsigned short* __restrict__ qbf) {
    int n = blockIdx.x * 16 + (threadIdx.x >> 4);
    int c16 = threadIdx.x & 15;
    int k = 8191 - (int)(unsigned)(partial[n] & 0xFFFFFFFFu);
    ((float4*)qbf)[(size_t)n * 16 + c16] =
        ((const float4*)embbf)[(size_t)k * 16 + c16];
}

// 1x1 conv (128->16) + sigmoid, NHWC fp32 in -> NCHW fp32 out
__global__ __launch_bounds__(256) void dec2_kernel(
    const float* __restrict__ y, const float* __restrict__ w2,
    const float* __restrict__ b2, float* __restrict__ out) {
    __shared__ float ys[64 * 130];
    __shared__ float ws[16 * 128];
    int blk = blockIdx.x;  // 512 = B*H
    int h = blk & 63;
    int b = blk >> 6;
    const float* yrow = y + (size_t)((b * H_ + h) * W_) * 128;
    for (int i = threadIdx.x; i < 64 * 64; i += 256) {
        int w = i >> 6, dh = i & 63;
        *(float2*)&ys[w * 130 + dh * 2] = *(const float2*)&yrow[w * 128 + dh * 2];
    }
    for (int i = threadIdx.x; i < 2048; i += 256) ws[i] = w2[i];
    __syncthreads();

    int w = threadIdx.x & 63;
    int c0 = (threadIdx.x >> 6) * 4;
    float acc[4] = {b2[c0], b2[c0 + 1], b2[c0 + 2], b2[c0 + 3]};
#pragma unroll 1
    for (int ci = 0; ci < 128; ci += 2) {
        float2 yv = *(const float2*)&ys[w * 130 + ci];
#pragma unroll
        for (int jc = 0; jc < 4; ++jc) {
            float2 wv = *(const float2*)&ws[(c0 + jc) * 128 + ci];
            acc[jc] += yv.x * wv.x + yv.y * wv.y;
        }
    }
#pragma unroll
    for (int jc = 0; jc < 4; ++jc) {
        float v = 1.0f / (1.0f + expf(-acc[jc]));
        out[(((size_t)b * 16 + c0 + jc) * H_ + h) * W_ + w] = v;
    }
}

// ---------------------------------------------------------------------------
extern "C" void kernel_launch(void* const* d_in, const int* in_sizes, int n_in,
                              void* d_out, int out_size, void* d_ws,
                              size_t ws_size, hipStream_t stream) {
    const float* x = (const float*)d_in[0];
    const float* ew1 = (const float*)d_in[1];
    const float* eb1 = (const float*)d_in[2];
    const float* ew2 = (const float*)d_in[3];
    const float* eb2 = (const float*)d_in[4];
    const float* embed = (const float*)d_in[5];
    const float* dw1 = (const float*)d_in[6];
    const float* db1 = (const float*)d_in[7];
    const float* dw2 = (const float*)d_in[8];
    const float* db2 = (const float*)d_in[9];
    float* out = (float*)d_out;

    float* e2 = (float*)d_ws;                              // 8192 f
    float* dec1out = e2 + 8192;                            // 4194304 f
    unsigned long long* partial =
        (unsigned long long*)(dec1out + 4194304);          // 32768 u64
    unsigned short* xtbf = (unsigned short*)(partial + 32768);  // 524288 us
    unsigned short* wtb1b = xtbf + 524288;                 // 20480 us
    unsigned short* wtbf2 = wtb1b + 20480;                 // 147456 us
    unsigned short* wtbf3 = wtbf2 + 147456;                // 147456 us
    unsigned short* embbf = wtbf3 + 147456;                // 1048576 us
    unsigned short* abf = embbf + 1048576;                 // 4194304 us
    unsigned short* flatbf = abf + 4194304;                // 4194304 us
    unsigned short* qbf = flatbf + 4194304;                // 4194304 us

    prep_kernel<<<4464, 256, 0, stream>>>(x, ew1, ew2, dw1, embed, xtbf, wtbf2,
                                          wtbf3, e2, embbf, wtb1b, partial);
    conv1_mfma_kernel<<<512, 256, 0, stream>>>(xtbf, wtb1b, eb1, abf);
    conv3x3_mfma_kernel<true><<<512, 256, 0, stream>>>(abf, wtbf2, eb2, flatbf);
    vq_mfma_kernel<<<1024, 256, 0, stream>>>(flatbf, embbf, e2, partial);
    gather_bf16_kernel<<<2048, 256, 0, stream>>>(embbf, partial, qbf);
    conv3x3_mfma_kernel<false><<<512, 256, 0, stream>>>(qbf, wtbf3, db1,
                                                        dec1out);
    dec2_kernel<<<512, 256, 0, stream>>>(dec1out, dw2, db2, out);
}

// Round 7
// 294.282 us; speedup vs baseline: 1.4825x; 1.4825x over previous
//
#include <hip/hip_runtime.h>

// Problem constants
constexpr int B_ = 8, H_ = 64, W_ = 64, C0 = 16, D_ = 128, K_ = 8192;
constexpr int N_ = B_ * H_ * W_;  // 32768 pixels

typedef __attribute__((ext_vector_type(8))) short short8;  // 8 bf16
typedef __attribute__((ext_vector_type(4))) float f32x4;   // MFMA C/D

__device__ __forceinline__ float gelu_f(float x) {
    return 0.5f * x * (1.0f + erff(x * 0.70710678118654752440f));
}

__device__ __forceinline__ unsigned short f2bf(float f) {  // RNE f32->bf16
    unsigned u = __float_as_uint(f);
    u += 0x7fffu + ((u >> 16) & 1u);
    return (unsigned short)(u >> 16);
}

// ---------------------------------------------------------------------------
// One fused prep kernel (block-range switched):
//  A [0,2048):      x NCHW f32 -> xtbf NHWC bf16
//  B [2048,2624):   ew2 OIHW -> wtbf2 [t][co][ci] bf16
//  C [2624,3200):   dw1 OIHW -> wtbf3 [t][co][ci] bf16
//  D [3200,3232):   e2[k] = ||embed_k||^2 (fp32)
//  E [3232,4256):   embed f32 -> embbf bf16
//  F [4256,4336):   ew1 OIHW -> wtb1b [co][kk=t*16+ci, pad 160] bf16
//  G [4336,4464):   partial[n] = 0 (VQ cross-block atomic-merge slots)
__global__ __launch_bounds__(256) void prep_kernel(
    const float* __restrict__ x, const float* __restrict__ ew1,
    const float* __restrict__ ew2, const float* __restrict__ dw1,
    const float* __restrict__ embed, unsigned short* __restrict__ xtbf,
    unsigned short* __restrict__ wtbf2, unsigned short* __restrict__ wtbf3,
    float* __restrict__ e2, unsigned short* __restrict__ embbf,
    unsigned short* __restrict__ wtb1b,
    unsigned long long* __restrict__ partial) {
    int blk = blockIdx.x;
    int tid = threadIdx.x;
    if (blk < 2048) {  // A: xtbf (out-contiguous)
        int j = blk * 256 + tid;
        int c = j & 15, w = (j >> 4) & 63, h = (j >> 10) & 63, b = j >> 16;
        xtbf[j] = f2bf(x[(((b << 4) + c) << 12) + (h << 6) + w]);
    } else if (blk < 3200) {  // B/C: 3x3 128-ch weights -> [t][co][ci] bf16
        const float* src = (blk < 2624) ? ew2 : dw1;
        unsigned short* dst = (blk < 2624) ? wtbf2 : wtbf3;
        int i = (blk - ((blk < 2624) ? 2048 : 2624)) * 256 + tid;
        int ci = i & 127, co = (i >> 7) & 127, t = i >> 14;
        dst[i] = f2bf(src[(co * 128 + ci) * 9 + t]);
    } else if (blk < 3232) {  // D: e2
        int k = (blk - 3200) * 256 + tid;
        const float4* e4 = (const float4*)(embed + (size_t)k * 128);
        float s = 0.0f;
#pragma unroll 8
        for (int i = 0; i < 32; ++i) {
            float4 v = e4[i];
            s += v.x * v.x + v.y * v.y + v.z * v.z + v.w * v.w;
        }
        e2[k] = s;
    } else if (blk < 4256) {  // E: embbf
        int i = (blk - 3232) * 256 + tid;
        float4 v = ((const float4*)embed)[i];
        uint2 o;
        o.x = (unsigned)f2bf(v.x) | ((unsigned)f2bf(v.y) << 16);
        o.y = (unsigned)f2bf(v.z) | ((unsigned)f2bf(v.w) << 16);
        ((uint2*)embbf)[i] = o;
    } else if (blk < 4336) {  // F: wtb1b [128 co][160 kk]
        int i = (blk - 4256) * 256 + tid;  // < 20480
        int co = i / 160, kk = i % 160;
        float v = 0.0f;
        if (kk < 144) {
            int t = kk >> 4, ci = kk & 15;
            v = ew1[(co * 16 + ci) * 9 + t];
        }
        wtb1b[i] = f2bf(v);
    } else {  // G: zero the VQ merge slots (poisoned 0xAA by harness)
        int i = (blk - 4336) * 256 + tid;  // < 32768
        partial[i] = 0ULL;
    }
}

// ---------------------------------------------------------------------------
// conv1: 16->128 3x3 + GELU via MFMA, K=160 (9 taps x 16 ci, zero-padded).
__global__ __launch_bounds__(256, 2) void conv1_mfma_kernel(
    const unsigned short* __restrict__ xtbf,   // NHWC [B,64,64,16] bf16
    const unsigned short* __restrict__ wtb1b,  // [128][160] bf16
    const float* __restrict__ bias,            // [128]
    unsigned short* __restrict__ out) {        // NHWC [B,64,64,128] bf16
    constexpr int LDA = 168;
    __shared__ __align__(16) unsigned short As[64 * LDA];  // 21504 B
    int tid = threadIdx.x;
    int wv = tid >> 6, lane = tid & 63;
    int r = lane & 15, q = lane >> 4;
    int h0 = blockIdx.x & 63, b = blockIdx.x >> 6;

#pragma unroll
    for (int j = 0; j < 5; ++j) {
        int s = tid + j * 256;
        if (s < 1152) {
            int px = s / 18, rem = s % 18;
            int t = rem >> 1, half = rem & 1;
            int hh = h0 + t / 3 - 1, ww = px + t % 3 - 1;
            float4 v = make_float4(0.f, 0.f, 0.f, 0.f);
            if ((unsigned)hh < 64u && (unsigned)ww < 64u)
                v = *(const float4*)(xtbf + (((b * 64 + hh) * 64 + ww) << 4) +
                                     half * 8);
            *(float4*)(As + px * LDA + t * 16 + half * 8) = v;
        } else {
            int z = s - 1152;  // < 128
            int px = z >> 1, half = z & 1;
            *(float4*)(As + px * LDA + 144 + half * 8) =
                make_float4(0.f, 0.f, 0.f, 0.f);
        }
    }
    __syncthreads();

    f32x4 acc[4][2];
#pragma unroll
    for (int ms = 0; ms < 4; ++ms)
#pragma unroll
        for (int ns = 0; ns < 2; ++ns) acc[ms][ns] = (f32x4){0.f, 0.f, 0.f, 0.f};

#pragma unroll
    for (int k = 0; k < 5; ++k) {
        short8 af[4], bf[2];
#pragma unroll
        for (int ms = 0; ms < 4; ++ms)
            af[ms] = *(const short8*)(As + (ms * 16 + r) * LDA + k * 32 + q * 8);
#pragma unroll
        for (int ns = 0; ns < 2; ++ns) {
            int co = wv * 32 + ns * 16 + r;
            bf[ns] = *(const short8*)(wtb1b + co * 160 + k * 32 + q * 8);
        }
#pragma unroll
        for (int ms = 0; ms < 4; ++ms)
#pragma unroll
            for (int ns = 0; ns < 2; ++ns)
                acc[ms][ns] = __builtin_amdgcn_mfma_f32_16x16x32_bf16(
                    af[ms], bf[ns], acc[ms][ns], 0, 0, 0);
    }

#pragma unroll
    for (int ns = 0; ns < 2; ++ns) {
        int co = wv * 32 + ns * 16 + r;
        float bv = bias[co];
#pragma unroll
        for (int ms = 0; ms < 4; ++ms)
#pragma unroll
            for (int rg = 0; rg < 4; ++rg) {
                int px = ms * 16 + q * 4 + rg;
                int pix = (b * 64 + h0) * 64 + px;
                out[(size_t)pix * 128 + co] = f2bf(gelu_f(acc[ms][ns][rg] + bv));
            }
    }
}

// ---------------------------------------------------------------------------
// 3x3 128->128 conv + GELU via MFMA; halo staged once, weights from L2.
template <bool OUT_BF16>
__global__ __launch_bounds__(256, 2) void conv3x3_mfma_kernel(
    const unsigned short* __restrict__ in,   // NHWC [B,64,64,128] bf16
    const unsigned short* __restrict__ wtb,  // [9][co][ci] bf16
    const float* __restrict__ bias,          // [128]
    void* __restrict__ out_) {               // NHWC fp32 or bf16
    constexpr int LDC = 136;
    __shared__ __align__(16) unsigned short As[3 * 66 * LDC];  // 53856 B
    int tid = threadIdx.x;
    int wv = tid >> 6, lane = tid & 63;
    int r = lane & 15, q = lane >> 4;
    int h0 = blockIdx.x & 63, b = blockIdx.x >> 6;

    for (int j = 0; j < 13; ++j) {
        int s = tid + j * 256;
        if (s < 3168) {
            int col = s >> 4, chunk = s & 15;
            int ry = col / 66, cx = col % 66;
            int hh = h0 - 1 + ry, ww = cx - 1;
            float4 v = make_float4(0.f, 0.f, 0.f, 0.f);
            if ((unsigned)hh < 64u && (unsigned)ww < 64u)
                v = *(const float4*)(in + ((size_t)((b * 64 + hh) * 64 + ww))
                                              * 128 + chunk * 8);
            *(float4*)(As + col * LDC + chunk * 8) = v;
        }
    }
    __syncthreads();

    f32x4 acc[4][2];
#pragma unroll
    for (int ms = 0; ms < 4; ++ms)
#pragma unroll
        for (int ns = 0; ns < 2; ++ns) acc[ms][ns] = (f32x4){0.f, 0.f, 0.f, 0.f};

    for (int t = 0; t < 9; ++t) {
        int dy = t / 3, dx = t % 3;
        const unsigned short* wsrc = wtb + t * 16384;
#pragma unroll
        for (int k = 0; k < 4; ++k) {
            short8 af[4], bf[2];
#pragma unroll
            for (int ms = 0; ms < 4; ++ms) {
                int col = dy * 66 + ms * 16 + r + dx;
                af[ms] = *(const short8*)(As + col * LDC + k * 32 + q * 8);
            }
#pragma unroll
            for (int ns = 0; ns < 2; ++ns) {
                int co = wv * 32 + ns * 16 + r;
                bf[ns] = *(const short8*)(wsrc + co * 128 + k * 32 + q * 8);
            }
#pragma unroll
            for (int ms = 0; ms < 4; ++ms)
#pragma unroll
                for (int ns = 0; ns < 2; ++ns)
                    acc[ms][ns] = __builtin_amdgcn_mfma_f32_16x16x32_bf16(
                        af[ms], bf[ns], acc[ms][ns], 0, 0, 0);
        }
    }

#pragma unroll
    for (int ns = 0; ns < 2; ++ns) {
        int co = wv * 32 + ns * 16 + r;
        float bv = bias[co];
#pragma unroll
        for (int ms = 0; ms < 4; ++ms)
#pragma unroll
            for (int rg = 0; rg < 4; ++rg) {
                int px = ms * 16 + q * 4 + rg;
                int pix = (b * 64 + h0) * 64 + px;
                float g = gelu_f(acc[ms][ns][rg] + bv);
                if (OUT_BF16)
                    ((unsigned short*)out_)[(size_t)pix * 128 + co] = f2bf(g);
                else
                    ((float*)out_)[(size_t)pix * 128 + co] = g;
            }
    }
}

// ---------------------------------------------------------------------------
// VQ argmin via bf16 MFMA, K-split x2 (1024 blocks -> 4 blocks/CU).
// R6 post-mortem: __launch_bounds__(256,4) capped VGPR at 64 and spilled
// (FETCH 621 MB). Keep (256,2): 88 VGPR, no spill; occupancy comes from the
// grid (4 blocks/CU co-resident: LDS 4x33 KB=133<160, 4x88=352<512 VGPR/SIMD).
// acc init = -e2/2 -> score = f.e - e2/2, argMAX. Low 7 mantissa bits carry
// key (larger key = smaller code) -> single v_max_f32 running argmax.
// Cross-block merge: atomicMax on packed (sortable_score<<32 | (8191-code)).
__global__ __launch_bounds__(256, 2) void vq_mfma_kernel(
    const unsigned short* __restrict__ flatbf,  // [N][128] bf16
    const unsigned short* __restrict__ embbf,   // [K][128] bf16
    const float* __restrict__ e2,               // [K] fp32
    unsigned long long* __restrict__ partial) { // [N] packed, zero-inited
    constexpr int LDA = 136;
    __shared__ __align__(16) unsigned short SH[16640];  // 33280 B (stage+merge)
    int tid = threadIdx.x;
    int wv = tid >> 6, lane = tid & 63;
    int r = lane & 15, q = lane >> 4;
    int half = blockIdx.x & 1;
    int m0 = (blockIdx.x >> 1) * 64;
    int kbase = half * 4096;

    // stage A (64 px x 128 d) and preload frags to registers
#pragma unroll
    for (int j = 0; j < 4; ++j) {
        int row = j * 16 + (tid >> 4), col = tid & 15;
        float4 v = *(const float4*)(flatbf + (size_t)(m0 + row) * 128 + col * 8);
        *(float4*)(SH + row * LDA + col * 8) = v;
    }
    __syncthreads();
    short8 afr[4][4];  // [ms][k]
#pragma unroll
    for (int ms = 0; ms < 4; ++ms)
#pragma unroll
        for (int k = 0; k < 4; ++k)
            afr[ms][k] = *(const short8*)(SH + (ms * 16 + r) * LDA + k * 32 + q * 8);
    __syncthreads();  // all waves done reading A; SH reusable for merge

    float best[4][4];
#pragma unroll
    for (int ms = 0; ms < 4; ++ms)
#pragma unroll
        for (int rg = 0; rg < 4; ++rg) best[ms][rg] = -3.4e38f;

    const unsigned short* bp = embbf + (size_t)(kbase + wv * 64 + r) * 128 + q * 8;
    const float* e2p = e2 + kbase + wv * 64 + r;

    for (int it = 0; it < 16; ++it) {
        float e2v[4];
#pragma unroll
        for (int ns = 0; ns < 4; ++ns) e2v[ns] = e2p[it * 256 + ns * 16];

        f32x4 acc[4][4];  // [ms][ns], init -e2/2
#pragma unroll
        for (int ns = 0; ns < 4; ++ns) {
            float v = -0.5f * e2v[ns];
#pragma unroll
            for (int ms = 0; ms < 4; ++ms) acc[ms][ns] = (f32x4){v, v, v, v};
        }

#pragma unroll
        for (int k = 0; k < 4; ++k) {
            short8 bfr[4];
#pragma unroll
            for (int ns = 0; ns < 4; ++ns)
                bfr[ns] = *(const short8*)(bp + (size_t)it * 32768 + ns * 2048 +
                                           k * 32);
#pragma unroll
            for (int ms = 0; ms < 4; ++ms)
#pragma unroll
                for (int ns = 0; ns < 4; ++ns)
                    acc[ms][ns] = __builtin_amdgcn_mfma_f32_16x16x32_bf16(
                        afr[ms][k], bfr[ns], acc[ms][ns], 0, 0, 0);
        }

#pragma unroll
        for (int ns = 0; ns < 4; ++ns) {
            unsigned key = 127u - (unsigned)(it * 4 + ns);
#pragma unroll
            for (int ms = 0; ms < 4; ++ms)
#pragma unroll
                for (int rg = 0; rg < 4; ++rg) {
                    unsigned u = (__float_as_uint(acc[ms][ns][rg]) & 0xFFFFFF80u)
                                 | key;
                    best[ms][rg] = fmaxf(best[ms][rg], __uint_as_float(u));
                }
        }
    }

    // in-block merge of 64 candidates/pixel via LDS
    float* sred = (float*)SH;      // [64][65] floats
    int* ired = (int*)SH + 4160;   // [64][65] ints
    int cand = wv * 16 + r;
#pragma unroll
    for (int ms = 0; ms < 4; ++ms)
#pragma unroll
        for (int rg = 0; rg < 4; ++rg) {
            unsigned bits = __float_as_uint(best[ms][rg]);
            unsigned keyinv = 127u - (bits & 127u);
            int code = kbase + (int)(keyinv >> 2) * 256 + wv * 64 +
                       (int)(keyinv & 3u) * 16 + r;
            int pixel = ms * 16 + q * 4 + rg;
            sred[pixel * 65 + cand] = best[ms][rg];
            ired[pixel * 65 + cand] = code;
        }
    __syncthreads();
    if (tid < 64) {
        float bs = sred[tid * 65];
        int bi = ired[tid * 65];
        for (int c = 1; c < 64; ++c) {
            float s = sred[tid * 65 + c];
            int i2 = ired[tid * 65 + c];
            if (s > bs || (s == bs && i2 < bi)) {
                bs = s;
                bi = i2;
            }
        }
        // cross-block merge: monotone float->uint, larger = better score;
        // low field (8191-code) makes ties pick the smaller code.
        unsigned sb = __float_as_uint(bs);
        sb = (sb & 0x80000000u) ? ~sb : (sb | 0x80000000u);
        unsigned long long packed =
            ((unsigned long long)sb << 32) | (unsigned)(8191 - bi);
        atomicMax(partial + m0 + tid, packed);
    }
}

// ---------------------------------------------------------------------------
__global__ __launch_bounds__(256) void gather_bf16_kernel(
    const unsigned short* __restrict__ embbf,
    const unsigned long long* __restrict__ partial,
    unsigned short* __restrict__ qbf) {
    int n = blockIdx.x * 16 + (threadIdx.x >> 4);
    int c16 = threadIdx.x & 15;
    int k = 8191 - (int)(unsigned)(partial[n] & 0xFFFFFFFFu);
    ((float4*)qbf)[(size_t)n * 16 + c16] =
        ((const float4*)embbf)[(size_t)k * 16 + c16];
}

// 1x1 conv (128->16) + sigmoid, NHWC fp32 in -> NCHW fp32 out
__global__ __launch_bounds__(256) void dec2_kernel(
    const float* __restrict__ y, const float* __restrict__ w2,
    const float* __restrict__ b2, float* __restrict__ out) {
    __shared__ float ys[64 * 130];
    __shared__ float ws[16 * 128];
    int blk = blockIdx.x;  // 512 = B*H
    int h = blk & 63;
    int b = blk >> 6;
    const float* yrow = y + (size_t)((b * H_ + h) * W_) * 128;
    for (int i = threadIdx.x; i < 64 * 64; i += 256) {
        int w = i >> 6, dh = i & 63;
        *(float2*)&ys[w * 130 + dh * 2] = *(const float2*)&yrow[w * 128 + dh * 2];
    }
    for (int i = threadIdx.x; i < 2048; i += 256) ws[i] = w2[i];
    __syncthreads();

    int w = threadIdx.x & 63;
    int c0 = (threadIdx.x >> 6) * 4;
    float acc[4] = {b2[c0], b2[c0 + 1], b2[c0 + 2], b2[c0 + 3]};
#pragma unroll 1
    for (int ci = 0; ci < 128; ci += 2) {
        float2 yv = *(const float2*)&ys[w * 130 + ci];
#pragma unroll
        for (int jc = 0; jc < 4; ++jc) {
            float2 wv = *(const float2*)&ws[(c0 + jc) * 128 + ci];
            acc[jc] += yv.x * wv.x + yv.y * wv.y;
        }
    }
#pragma unroll
    for (int jc = 0; jc < 4; ++jc) {
        float v = 1.0f / (1.0f + expf(-acc[jc]));
        out[(((size_t)b * 16 + c0 + jc) * H_ + h) * W_ + w] = v;
    }
}

// ---------------------------------------------------------------------------
extern "C" void kernel_launch(void* const* d_in, const int* in_sizes, int n_in,
                              void* d_out, int out_size, void* d_ws,
                              size_t ws_size, hipStream_t stream) {
    const float* x = (const float*)d_in[0];
    const float* ew1 = (const float*)d_in[1];
    const float* eb1 = (const float*)d_in[2];
    const float* ew2 = (const float*)d_in[3];
    const float* eb2 = (const float*)d_in[4];
    const float* embed = (const float*)d_in[5];
    const float* dw1 = (const float*)d_in[6];
    const float* db1 = (const float*)d_in[7];
    const float* dw2 = (const float*)d_in[8];
    const float* db2 = (const float*)d_in[9];
    float* out = (float*)d_out;

    float* e2 = (float*)d_ws;                              // 8192 f
    float* dec1out = e2 + 8192;                            // 4194304 f
    unsigned long long* partial =
        (unsigned long long*)(dec1out + 4194304);          // 32768 u64
    unsigned short* xtbf = (unsigned short*)(partial + 32768);  // 524288 us
    unsigned short* wtb1b = xtbf + 524288;                 // 20480 us
    unsigned short* wtbf2 = wtb1b + 20480;                 // 147456 us
    unsigned short* wtbf3 = wtbf2 + 147456;                // 147456 us
    unsigned short* embbf = wtbf3 + 147456;                // 1048576 us
    unsigned short* abf = embbf + 1048576;                 // 4194304 us
    unsigned short* flatbf = abf + 4194304;                // 4194304 us
    unsigned short* qbf = flatbf + 4194304;                // 4194304 us

    prep_kernel<<<4464, 256, 0, stream>>>(x, ew1, ew2, dw1, embed, xtbf, wtbf2,
                                          wtbf3, e2, embbf, wtb1b, partial);
    conv1_mfma_kernel<<<512, 256, 0, stream>>>(xtbf, wtb1b, eb1, abf);
    conv3x3_mfma_kernel<true><<<512, 256, 0, stream>>>(abf, wtbf2, eb2, flatbf);
    vq_mfma_kernel<<<1024, 256, 0, stream>>>(flatbf, embbf, e2, partial);
    gather_bf16_kernel<<<2048, 256, 0, stream>>>(embbf, partial, qbf);
    conv3x3_mfma_kernel<false><<<512, 256, 0, stream>>>(qbf, wtbf3, db1,
                                                        dec1out);
    dec2_kernel<<<512, 256, 0, stream>>>(dec1out, dw2, db2, out);
}

// Round 8
// 281.528 us; speedup vs baseline: 1.5496x; 1.0453x over previous
//
#include <hip/hip_runtime.h>

// Problem constants
constexpr int B_ = 8, H_ = 64, W_ = 64, C0 = 16, D_ = 128, K_ = 8192;
constexpr int N_ = B_ * H_ * W_;  // 32768 pixels

typedef __attribute__((ext_vector_type(8))) short short8;  // 8 bf16
typedef __attribute__((ext_vector_type(4))) float f32x4;   // MFMA C/D

__device__ __forceinline__ float gelu_f(float x) {
    return 0.5f * x * (1.0f + erff(x * 0.70710678118654752440f));
}

__device__ __forceinline__ unsigned short f2bf(float f) {  // RNE f32->bf16
    unsigned u = __float_as_uint(f);
    u += 0x7fffu + ((u >> 16) & 1u);
    return (unsigned short)(u >> 16);
}

// ---------------------------------------------------------------------------
// One fused prep kernel (block-range switched):
//  A [0,2048):      x NCHW f32 -> xtbf NHWC bf16
//  B [2048,2624):   ew2 OIHW -> wtbf2 [t][co][ci] bf16
//  C [2624,3200):   dw1 OIHW -> wtbf3 [t][co][ci] bf16
//  D [3200,3232):   e2[k] = ||embed_k||^2 (fp32)
//  E [3232,4256):   embed f32 -> embbf bf16
//  F [4256,4336):   ew1 OIHW -> wtb1b [co][kk=t*16+ci, pad 160] bf16
//  G [4336,4464):   partial[n] = 0 (VQ cross-block atomic-merge slots)
__global__ __launch_bounds__(256) void prep_kernel(
    const float* __restrict__ x, const float* __restrict__ ew1,
    const float* __restrict__ ew2, const float* __restrict__ dw1,
    const float* __restrict__ embed, unsigned short* __restrict__ xtbf,
    unsigned short* __restrict__ wtbf2, unsigned short* __restrict__ wtbf3,
    float* __restrict__ e2, unsigned short* __restrict__ embbf,
    unsigned short* __restrict__ wtb1b,
    unsigned long long* __restrict__ partial) {
    int blk = blockIdx.x;
    int tid = threadIdx.x;
    if (blk < 2048) {  // A: xtbf (out-contiguous)
        int j = blk * 256 + tid;
        int c = j & 15, w = (j >> 4) & 63, h = (j >> 10) & 63, b = j >> 16;
        xtbf[j] = f2bf(x[(((b << 4) + c) << 12) + (h << 6) + w]);
    } else if (blk < 3200) {  // B/C: 3x3 128-ch weights -> [t][co][ci] bf16
        const float* src = (blk < 2624) ? ew2 : dw1;
        unsigned short* dst = (blk < 2624) ? wtbf2 : wtbf3;
        int i = (blk - ((blk < 2624) ? 2048 : 2624)) * 256 + tid;
        int ci = i & 127, co = (i >> 7) & 127, t = i >> 14;
        dst[i] = f2bf(src[(co * 128 + ci) * 9 + t]);
    } else if (blk < 3232) {  // D: e2
        int k = (blk - 3200) * 256 + tid;
        const float4* e4 = (const float4*)(embed + (size_t)k * 128);
        float s = 0.0f;
#pragma unroll 8
        for (int i = 0; i < 32; ++i) {
            float4 v = e4[i];
            s += v.x * v.x + v.y * v.y + v.z * v.z + v.w * v.w;
        }
        e2[k] = s;
    } else if (blk < 4256) {  // E: embbf
        int i = (blk - 3232) * 256 + tid;
        float4 v = ((const float4*)embed)[i];
        uint2 o;
        o.x = (unsigned)f2bf(v.x) | ((unsigned)f2bf(v.y) << 16);
        o.y = (unsigned)f2bf(v.z) | ((unsigned)f2bf(v.w) << 16);
        ((uint2*)embbf)[i] = o;
    } else if (blk < 4336) {  // F: wtb1b [128 co][160 kk]
        int i = (blk - 4256) * 256 + tid;  // < 20480
        int co = i / 160, kk = i % 160;
        float v = 0.0f;
        if (kk < 144) {
            int t = kk >> 4, ci = kk & 15;
            v = ew1[(co * 16 + ci) * 9 + t];
        }
        wtb1b[i] = f2bf(v);
    } else {  // G: zero the VQ merge slots (poisoned 0xAA by harness)
        int i = (blk - 4336) * 256 + tid;  // < 32768
        partial[i] = 0ULL;
    }
}

// ---------------------------------------------------------------------------
// conv1: 16->128 3x3 + GELU via MFMA, K=160 (9 taps x 16 ci, zero-padded).
__global__ __launch_bounds__(256, 2) void conv1_mfma_kernel(
    const unsigned short* __restrict__ xtbf,   // NHWC [B,64,64,16] bf16
    const unsigned short* __restrict__ wtb1b,  // [128][160] bf16
    const float* __restrict__ bias,            // [128]
    unsigned short* __restrict__ out) {        // NHWC [B,64,64,128] bf16
    constexpr int LDA = 168;
    __shared__ __align__(16) unsigned short As[64 * LDA];  // 21504 B
    int tid = threadIdx.x;
    int wv = tid >> 6, lane = tid & 63;
    int r = lane & 15, q = lane >> 4;
    int h0 = blockIdx.x & 63, b = blockIdx.x >> 6;

#pragma unroll
    for (int j = 0; j < 5; ++j) {
        int s = tid + j * 256;
        if (s < 1152) {
            int px = s / 18, rem = s % 18;
            int t = rem >> 1, half = rem & 1;
            int hh = h0 + t / 3 - 1, ww = px + t % 3 - 1;
            float4 v = make_float4(0.f, 0.f, 0.f, 0.f);
            if ((unsigned)hh < 64u && (unsigned)ww < 64u)
                v = *(const float4*)(xtbf + (((b * 64 + hh) * 64 + ww) << 4) +
                                     half * 8);
            *(float4*)(As + px * LDA + t * 16 + half * 8) = v;
        } else {
            int z = s - 1152;  // < 128
            int px = z >> 1, half = z & 1;
            *(float4*)(As + px * LDA + 144 + half * 8) =
                make_float4(0.f, 0.f, 0.f, 0.f);
        }
    }
    __syncthreads();

    f32x4 acc[4][2];
#pragma unroll
    for (int ms = 0; ms < 4; ++ms)
#pragma unroll
        for (int ns = 0; ns < 2; ++ns) acc[ms][ns] = (f32x4){0.f, 0.f, 0.f, 0.f};

#pragma unroll
    for (int k = 0; k < 5; ++k) {
        short8 af[4], bf[2];
#pragma unroll
        for (int ms = 0; ms < 4; ++ms)
            af[ms] = *(const short8*)(As + (ms * 16 + r) * LDA + k * 32 + q * 8);
#pragma unroll
        for (int ns = 0; ns < 2; ++ns) {
            int co = wv * 32 + ns * 16 + r;
            bf[ns] = *(const short8*)(wtb1b + co * 160 + k * 32 + q * 8);
        }
#pragma unroll
        for (int ms = 0; ms < 4; ++ms)
#pragma unroll
            for (int ns = 0; ns < 2; ++ns)
                acc[ms][ns] = __builtin_amdgcn_mfma_f32_16x16x32_bf16(
                    af[ms], bf[ns], acc[ms][ns], 0, 0, 0);
    }

#pragma unroll
    for (int ns = 0; ns < 2; ++ns) {
        int co = wv * 32 + ns * 16 + r;
        float bv = bias[co];
#pragma unroll
        for (int ms = 0; ms < 4; ++ms)
#pragma unroll
            for (int rg = 0; rg < 4; ++rg) {
                int px = ms * 16 + q * 4 + rg;
                int pix = (b * 64 + h0) * 64 + px;
                out[(size_t)pix * 128 + co] = f2bf(gelu_f(acc[ms][ns][rg] + bv));
            }
    }
}

// ---------------------------------------------------------------------------
// 3x3 128->128 conv + GELU via MFMA; halo staged once, weights from L2.
// GATHER: A-pixels fetched indirectly through the VQ result (fuses the
// codebook gather into the decoder conv; removes the qbf buffer+kernel).
template <bool OUT_BF16, bool GATHER>
__global__ __launch_bounds__(256, 2) void conv3x3_mfma_kernel(
    const unsigned short* __restrict__ in,   // NHWC acts, or embbf if GATHER
    const unsigned long long* __restrict__ gidx,  // packed VQ result or null
    const unsigned short* __restrict__ wtb,  // [9][co][ci] bf16
    const float* __restrict__ bias,          // [128]
    void* __restrict__ out_) {               // NHWC fp32 or bf16
    constexpr int LDC = 136;
    __shared__ __align__(16) unsigned short As[3 * 66 * LDC];  // 53856 B
    int tid = threadIdx.x;
    int wv = tid >> 6, lane = tid & 63;
    int r = lane & 15, q = lane >> 4;
    int h0 = blockIdx.x & 63, b = blockIdx.x >> 6;

    for (int j = 0; j < 13; ++j) {
        int s = tid + j * 256;
        if (s < 3168) {
            int col = s >> 4, chunk = s & 15;
            int ry = col / 66, cx = col % 66;
            int hh = h0 - 1 + ry, ww = cx - 1;
            float4 v = make_float4(0.f, 0.f, 0.f, 0.f);
            if ((unsigned)hh < 64u && (unsigned)ww < 64u) {
                int pix = (b * 64 + hh) * 64 + ww;
                const unsigned short* src;
                if (GATHER) {
                    int k = 8191 - (int)(unsigned)(gidx[pix] & 0xFFFFFFFFu);
                    src = in + (size_t)k * 128;
                } else {
                    src = in + (size_t)pix * 128;
                }
                v = *(const float4*)(src + chunk * 8);
            }
            *(float4*)(As + col * LDC + chunk * 8) = v;
        }
    }
    __syncthreads();

    f32x4 acc[4][2];
#pragma unroll
    for (int ms = 0; ms < 4; ++ms)
#pragma unroll
        for (int ns = 0; ns < 2; ++ns) acc[ms][ns] = (f32x4){0.f, 0.f, 0.f, 0.f};

    for (int t = 0; t < 9; ++t) {
        int dy = t / 3, dx = t % 3;
        const unsigned short* wsrc = wtb + t * 16384;
#pragma unroll
        for (int k = 0; k < 4; ++k) {
            short8 af[4], bf[2];
#pragma unroll
            for (int ms = 0; ms < 4; ++ms) {
                int col = dy * 66 + ms * 16 + r + dx;
                af[ms] = *(const short8*)(As + col * LDC + k * 32 + q * 8);
            }
#pragma unroll
            for (int ns = 0; ns < 2; ++ns) {
                int co = wv * 32 + ns * 16 + r;
                bf[ns] = *(const short8*)(wsrc + co * 128 + k * 32 + q * 8);
            }
#pragma unroll
            for (int ms = 0; ms < 4; ++ms)
#pragma unroll
                for (int ns = 0; ns < 2; ++ns)
                    acc[ms][ns] = __builtin_amdgcn_mfma_f32_16x16x32_bf16(
                        af[ms], bf[ns], acc[ms][ns], 0, 0, 0);
        }
    }

#pragma unroll
    for (int ns = 0; ns < 2; ++ns) {
        int co = wv * 32 + ns * 16 + r;
        float bv = bias[co];
#pragma unroll
        for (int ms = 0; ms < 4; ++ms)
#pragma unroll
            for (int rg = 0; rg < 4; ++rg) {
                int px = ms * 16 + q * 4 + rg;
                int pix = (b * 64 + h0) * 64 + px;
                float g = gelu_f(acc[ms][ns][rg] + bv);
                if (OUT_BF16)
                    ((unsigned short*)out_)[(size_t)pix * 128 + co] = f2bf(g);
                else
                    ((float*)out_)[(size_t)pix * 128 + co] = g;
            }
    }
}

// ---------------------------------------------------------------------------
// VQ argmin via bf16 MFMA, K-split x2 (1024 blocks), register-lean + software
// pipelined (R7 post-mortem: afr[4][4]+acc = ~170 unified VGPRs capped the CU
// at 2 waves/SIMD; per-group loads issued right before their MFMAs serialized
// ~200cyc L2 latency). Changes: A-frags re-read from LDS per k-group; A(LDS)
// and B(global) frags ping-pong-prefetched one group ahead so loads overlap
// the previous group's 16 MFMAs. Key = 10 bits (it,ns,r) in low mantissa ->
// single v_max_f32 argmax + in-wave shfl_xor merge over the 16 r-lanes.
// Cross-block merge: atomicMax on packed (sortable_score<<32 | (8191-code)).
__global__ __launch_bounds__(256, 2) void vq_mfma_kernel(
    const unsigned short* __restrict__ flatbf,  // [N][128] bf16
    const unsigned short* __restrict__ embbf,   // [K][128] bf16
    const float* __restrict__ e2,               // [K] fp32
    unsigned long long* __restrict__ partial) { // [N] packed, zero-inited
    constexpr int LDA = 136;
    __shared__ __align__(16) unsigned short As[64 * LDA];   // 17408 B
    __shared__ unsigned long long merged[64][4];            // 2048 B
    int tid = threadIdx.x;
    int wv = tid >> 6, lane = tid & 63;
    int r = lane & 15, q = lane >> 4;
    int half = blockIdx.x & 1;
    int m0 = (blockIdx.x >> 1) * 64;
    int kbase = half * 4096;

    // stage A (64 px x 128 d); stays resident in LDS for the whole kernel
#pragma unroll
    for (int j = 0; j < 4; ++j) {
        int row = j * 16 + (tid >> 4), col = tid & 15;
        float4 v = *(const float4*)(flatbf + (size_t)(m0 + row) * 128 + col * 8);
        *(float4*)(As + row * LDA + col * 8) = v;
    }
    __syncthreads();

    const unsigned short* bp =
        embbf + (size_t)(kbase + wv * 64 + r) * 128 + q * 8;
    const float* e2p = e2 + kbase + wv * 64 + r;

    float best[4][4];
#pragma unroll
    for (int ms = 0; ms < 4; ++ms)
#pragma unroll
        for (int rg = 0; rg < 4; ++rg) best[ms][rg] = -3.4e38f;

    short8 af[2][4], bf[2][4];
    float e2v[4];
    // prologue: group 0 frags + e2 for it=0
#pragma unroll
    for (int ms = 0; ms < 4; ++ms)
        af[0][ms] = *(const short8*)(As + (ms * 16 + r) * LDA + q * 8);
#pragma unroll
    for (int ns = 0; ns < 4; ++ns) bf[0][ns] = *(const short8*)(bp + ns * 2048);
#pragma unroll
    for (int ns = 0; ns < 4; ++ns) e2v[ns] = e2p[ns * 16];

    f32x4 acc[4][4];
#pragma unroll
    for (int ns = 0; ns < 4; ++ns) {
        float v = -0.5f * e2v[ns];
#pragma unroll
        for (int ms = 0; ms < 4; ++ms) acc[ms][ns] = (f32x4){v, v, v, v};
    }

    int key0 = 1023 - r;
#pragma unroll 4
    for (int g = 0; g < 64; ++g) {
        int cur = g & 1, nxt = cur ^ 1;
        int it = g >> 2, kk = g & 3;
        if (g < 63) {  // prefetch group g+1 (A from LDS, B from L2)
            int it1 = (g + 1) >> 2, kk1 = (g + 1) & 3;
#pragma unroll
            for (int ms = 0; ms < 4; ++ms)
                af[nxt][ms] = *(const short8*)(As + (ms * 16 + r) * LDA +
                                               kk1 * 32 + q * 8);
#pragma unroll
            for (int ns = 0; ns < 4; ++ns)
                bf[nxt][ns] = *(const short8*)(bp + (size_t)it1 * 32768 +
                                               ns * 2048 + kk1 * 32);
        }
        if (kk == 2 && it < 15) {  // e2 for next iter (consumed at reinit)
#pragma unroll
            for (int ns = 0; ns < 4; ++ns)
                e2v[ns] = e2p[(it + 1) * 256 + ns * 16];
        }
#pragma unroll
        for (int ms = 0; ms < 4; ++ms)
#pragma unroll
            for (int ns = 0; ns < 4; ++ns)
                acc[ms][ns] = __builtin_amdgcn_mfma_f32_16x16x32_bf16(
                    af[cur][ms], bf[cur][ns], acc[ms][ns], 0, 0, 0);
        if (kk == 3) {
            // epilogue: pack 10-bit key, running max
#pragma unroll
            for (int ns = 0; ns < 4; ++ns) {
                unsigned keyv = (unsigned)(key0 - (it * 64 + ns * 16));
#pragma unroll
                for (int ms = 0; ms < 4; ++ms)
#pragma unroll
                    for (int rg = 0; rg < 4; ++rg) {
                        unsigned u =
                            (__float_as_uint(acc[ms][ns][rg]) & 0xFFFFFC00u) |
                            keyv;
                        best[ms][rg] = fmaxf(best[ms][rg], __uint_as_float(u));
                    }
            }
            if (it < 15) {  // reinit acc for next iter
#pragma unroll
                for (int ns = 0; ns < 4; ++ns) {
                    float v = -0.5f * e2v[ns];
#pragma unroll
                    for (int ms = 0; ms < 4; ++ms)
                        acc[ms][ns] = (f32x4){v, v, v, v};
                }
            }
        }
    }

    // in-wave merge over the 16 r-lanes (key encodes it,ns,r -> recoverable)
#pragma unroll
    for (int ms = 0; ms < 4; ++ms)
#pragma unroll
        for (int rg = 0; rg < 4; ++rg) {
            float v = best[ms][rg];
#pragma unroll
            for (int m = 1; m < 16; m <<= 1)
                v = fmaxf(v, __shfl_xor(v, m));
            best[ms][rg] = v;
        }
    if (r == 0) {
#pragma unroll
        for (int ms = 0; ms < 4; ++ms)
#pragma unroll
            for (int rg = 0; rg < 4; ++rg) {
                unsigned bits = __float_as_uint(best[ms][rg]);
                int cand = 1023 - (int)(bits & 1023u);
                int code = kbase + wv * 64 + (cand >> 6) * 256 +
                           ((cand >> 4) & 3) * 16 + (cand & 15);
                unsigned sb =
                    (bits & 0x80000000u) ? ~bits : (bits | 0x80000000u);
                unsigned long long packed =
                    ((unsigned long long)sb << 32) | (unsigned)(8191 - code);
                merged[ms * 16 + q * 4 + rg][wv] = packed;
            }
    }
    __syncthreads();
    if (tid < 64) {
        unsigned long long bp0 = merged[tid][0];
        bp0 = bp0 > merged[tid][1] ? bp0 : merged[tid][1];
        bp0 = bp0 > merged[tid][2] ? bp0 : merged[tid][2];
        bp0 = bp0 > merged[tid][3] ? bp0 : merged[tid][3];
        atomicMax(partial + m0 + tid, bp0);
    }
}

// ---------------------------------------------------------------------------
// 1x1 conv (128->16) + sigmoid, NHWC fp32 in -> NCHW fp32 out
__global__ __launch_bounds__(256) void dec2_kernel(
    const float* __restrict__ y, const float* __restrict__ w2,
    const float* __restrict__ b2, float* __restrict__ out) {
    __shared__ float ys[64 * 130];
    __shared__ float ws[16 * 128];
    int blk = blockIdx.x;  // 512 = B*H
    int h = blk & 63;
    int b = blk >> 6;
    const float* yrow = y + (size_t)((b * H_ + h) * W_) * 128;
    for (int i = threadIdx.x; i < 64 * 64; i += 256) {
        int w = i >> 6, dh = i & 63;
        *(float2*)&ys[w * 130 + dh * 2] = *(const float2*)&yrow[w * 128 + dh * 2];
    }
    for (int i = threadIdx.x; i < 2048; i += 256) ws[i] = w2[i];
    __syncthreads();

    int w = threadIdx.x & 63;
    int c0 = (threadIdx.x >> 6) * 4;
    float acc[4] = {b2[c0], b2[c0 + 1], b2[c0 + 2], b2[c0 + 3]};
#pragma unroll 1
    for (int ci = 0; ci < 128; ci += 2) {
        float2 yv = *(const float2*)&ys[w * 130 + ci];
#pragma unroll
        for (int jc = 0; jc < 4; ++jc) {
            float2 wv = *(const float2*)&ws[(c0 + jc) * 128 + ci];
            acc[jc] += yv.x * wv.x + yv.y * wv.y;
        }
    }
#pragma unroll
    for (int jc = 0; jc < 4; ++jc) {
        float v = 1.0f / (1.0f + expf(-acc[jc]));
        out[(((size_t)b * 16 + c0 + jc) * H_ + h) * W_ + w] = v;
    }
}

// ---------------------------------------------------------------------------
extern "C" void kernel_launch(void* const* d_in, const int* in_sizes, int n_in,
                              void* d_out, int out_size, void* d_ws,
                              size_t ws_size, hipStream_t stream) {
    const float* x = (const float*)d_in[0];
    const float* ew1 = (const float*)d_in[1];
    const float* eb1 = (const float*)d_in[2];
    const float* ew2 = (const float*)d_in[3];
    const float* eb2 = (const float*)d_in[4];
    const float* embed = (const float*)d_in[5];
    const float* dw1 = (const float*)d_in[6];
    const float* db1 = (const float*)d_in[7];
    const float* dw2 = (const float*)d_in[8];
    const float* db2 = (const float*)d_in[9];
    float* out = (float*)d_out;

    float* e2 = (float*)d_ws;                              // 8192 f
    float* dec1out = e2 + 8192;                            // 4194304 f
    unsigned long long* partial =
        (unsigned long long*)(dec1out + 4194304);          // 32768 u64
    unsigned short* xtbf = (unsigned short*)(partial + 32768);  // 524288 us
    unsigned short* wtb1b = xtbf + 524288;                 // 20480 us
    unsigned short* wtbf2 = wtb1b + 20480;                 // 147456 us
    unsigned short* wtbf3 = wtbf2 + 147456;                // 147456 us
    unsigned short* embbf = wtbf3 + 147456;                // 1048576 us
    unsigned short* abf = embbf + 1048576;                 // 4194304 us
    unsigned short* flatbf = abf + 4194304;                // 4194304 us

    prep_kernel<<<4464, 256, 0, stream>>>(x, ew1, ew2, dw1, embed, xtbf, wtbf2,
                                          wtbf3, e2, embbf, wtb1b, partial);
    conv1_mfma_kernel<<<512, 256, 0, stream>>>(xtbf, wtb1b, eb1, abf);
    conv3x3_mfma_kernel<true, false><<<512, 256, 0, stream>>>(
        abf, nullptr, wtbf2, eb2, flatbf);
    vq_mfma_kernel<<<1024, 256, 0, stream>>>(flatbf, embbf, e2, partial);
    conv3x3_mfma_kernel<false, true><<<512, 256, 0, stream>>>(
        embbf, partial, wtbf3, db1, dec1out);
    dec2_kernel<<<512, 256, 0, stream>>>(dec1out, dw2, db2, out);
}

// Round 9
// 271.022 us; speedup vs baseline: 1.6097x; 1.0388x over previous
//
#include <hip/hip_runtime.h>

// Problem constants
constexpr int B_ = 8, H_ = 64, W_ = 64, C0 = 16, D_ = 128, K_ = 8192;
constexpr int N_ = B_ * H_ * W_;  // 32768 pixels

typedef __attribute__((ext_vector_type(8))) short short8;  // 8 bf16
typedef __attribute__((ext_vector_type(4))) float f32x4;   // MFMA C/D

__device__ __forceinline__ float gelu_f(float x) {
    return 0.5f * x * (1.0f + erff(x * 0.70710678118654752440f));
}

__device__ __forceinline__ unsigned short f2bf(float f) {  // RNE f32->bf16
    unsigned u = __float_as_uint(f);
    u += 0x7fffu + ((u >> 16) & 1u);
    return (unsigned short)(u >> 16);
}

// ---------------------------------------------------------------------------
// One fused prep kernel (block-range switched):
//  A [0,2048):      x NCHW f32 -> xtbf NHWC bf16
//  B [2048,2624):   ew2 OIHW -> wtbf2 [t][co][ci] bf16
//  C [2624,3200):   dw1 OIHW -> wtbf3 [t][co][ci] bf16
//  D [3200,3232):   e2n[k] = -0.5*||embed_k||^2 (fp32)
//  E [3232,4256):   embed f32 -> embbf bf16
//  F [4256,4336):   ew1 OIHW -> wtb1b [co][kk=t*16+ci, pad 160] bf16
//  G [4336,4464):   partial[n] = 0 (VQ cross-block atomic-merge slots)
__global__ __launch_bounds__(256) void prep_kernel(
    const float* __restrict__ x, const float* __restrict__ ew1,
    const float* __restrict__ ew2, const float* __restrict__ dw1,
    const float* __restrict__ embed, unsigned short* __restrict__ xtbf,
    unsigned short* __restrict__ wtbf2, unsigned short* __restrict__ wtbf3,
    float* __restrict__ e2n, unsigned short* __restrict__ embbf,
    unsigned short* __restrict__ wtb1b,
    unsigned long long* __restrict__ partial) {
    int blk = blockIdx.x;
    int tid = threadIdx.x;
    if (blk < 2048) {  // A: xtbf (out-contiguous)
        int j = blk * 256 + tid;
        int c = j & 15, w = (j >> 4) & 63, h = (j >> 10) & 63, b = j >> 16;
        xtbf[j] = f2bf(x[(((b << 4) + c) << 12) + (h << 6) + w]);
    } else if (blk < 3200) {  // B/C: 3x3 128-ch weights -> [t][co][ci] bf16
        const float* src = (blk < 2624) ? ew2 : dw1;
        unsigned short* dst = (blk < 2624) ? wtbf2 : wtbf3;
        int i = (blk - ((blk < 2624) ? 2048 : 2624)) * 256 + tid;
        int ci = i & 127, co = (i >> 7) & 127, t = i >> 14;
        dst[i] = f2bf(src[(co * 128 + ci) * 9 + t]);
    } else if (blk < 3232) {  // D: e2n = -||e||^2 / 2
        int k = (blk - 3200) * 256 + tid;
        const float4* e4 = (const float4*)(embed + (size_t)k * 128);
        float s = 0.0f;
#pragma unroll 8
        for (int i = 0; i < 32; ++i) {
            float4 v = e4[i];
            s += v.x * v.x + v.y * v.y + v.z * v.z + v.w * v.w;
        }
        e2n[k] = -0.5f * s;
    } else if (blk < 4256) {  // E: embbf
        int i = (blk - 3232) * 256 + tid;
        float4 v = ((const float4*)embed)[i];
        uint2 o;
        o.x = (unsigned)f2bf(v.x) | ((unsigned)f2bf(v.y) << 16);
        o.y = (unsigned)f2bf(v.z) | ((unsigned)f2bf(v.w) << 16);
        ((uint2*)embbf)[i] = o;
    } else if (blk < 4336) {  // F: wtb1b [128 co][160 kk]
        int i = (blk - 4256) * 256 + tid;  // < 20480
        int co = i / 160, kk = i % 160;
        float v = 0.0f;
        if (kk < 144) {
            int t = kk >> 4, ci = kk & 15;
            v = ew1[(co * 16 + ci) * 9 + t];
        }
        wtb1b[i] = f2bf(v);
    } else {  // G: zero the VQ merge slots (poisoned 0xAA by harness)
        int i = (blk - 4336) * 256 + tid;  // < 32768
        partial[i] = 0ULL;
    }
}

// ---------------------------------------------------------------------------
// conv1: 16->128 3x3 + GELU via MFMA, K=160 (9 taps x 16 ci, zero-padded).
// All 10 weight frags preloaded to regs before the staging barrier (latency
// fully hidden); MFMA loop touches LDS only.
__global__ __launch_bounds__(256, 2) void conv1_mfma_kernel(
    const unsigned short* __restrict__ xtbf,   // NHWC [B,64,64,16] bf16
    const unsigned short* __restrict__ wtb1b,  // [128][160] bf16
    const float* __restrict__ bias,            // [128]
    unsigned short* __restrict__ out) {        // NHWC [B,64,64,128] bf16
    constexpr int LDA = 168;
    __shared__ __align__(16) unsigned short As[64 * LDA];  // 21504 B
    int tid = threadIdx.x;
    int wv = tid >> 6, lane = tid & 63;
    int r = lane & 15, q = lane >> 4;
    int h0 = blockIdx.x & 63, b = blockIdx.x >> 6;

    // preload all weight frags (40 VGPRs) — covered by staging + barrier
    short8 bf1[5][2];
#pragma unroll
    for (int k = 0; k < 5; ++k)
#pragma unroll
        for (int ns = 0; ns < 2; ++ns)
            bf1[k][ns] = *(const short8*)(wtb1b + (wv * 32 + ns * 16 + r) * 160 +
                                          k * 32 + q * 8);

#pragma unroll
    for (int j = 0; j < 5; ++j) {
        int s = tid + j * 256;
        if (s < 1152) {
            int px = s / 18, rem = s % 18;
            int t = rem >> 1, half = rem & 1;
            int hh = h0 + t / 3 - 1, ww = px + t % 3 - 1;
            float4 v = make_float4(0.f, 0.f, 0.f, 0.f);
            if ((unsigned)hh < 64u && (unsigned)ww < 64u)
                v = *(const float4*)(xtbf + (((b * 64 + hh) * 64 + ww) << 4) +
                                     half * 8);
            *(float4*)(As + px * LDA + t * 16 + half * 8) = v;
        } else {
            int z = s - 1152;  // < 128
            int px = z >> 1, half = z & 1;
            *(float4*)(As + px * LDA + 144 + half * 8) =
                make_float4(0.f, 0.f, 0.f, 0.f);
        }
    }
    __syncthreads();

    f32x4 acc[4][2];
#pragma unroll
    for (int ms = 0; ms < 4; ++ms)
#pragma unroll
        for (int ns = 0; ns < 2; ++ns) acc[ms][ns] = (f32x4){0.f, 0.f, 0.f, 0.f};

#pragma unroll
    for (int k = 0; k < 5; ++k) {
        short8 af[4];
#pragma unroll
        for (int ms = 0; ms < 4; ++ms)
            af[ms] = *(const short8*)(As + (ms * 16 + r) * LDA + k * 32 + q * 8);
#pragma unroll
        for (int ms = 0; ms < 4; ++ms)
#pragma unroll
            for (int ns = 0; ns < 2; ++ns)
                acc[ms][ns] = __builtin_amdgcn_mfma_f32_16x16x32_bf16(
                    af[ms], bf1[k][ns], acc[ms][ns], 0, 0, 0);
    }

#pragma unroll
    for (int ns = 0; ns < 2; ++ns) {
        int co = wv * 32 + ns * 16 + r;
        float bv = bias[co];
#pragma unroll
        for (int ms = 0; ms < 4; ++ms)
#pragma unroll
            for (int rg = 0; rg < 4; ++rg) {
                int px = ms * 16 + q * 4 + rg;
                int pix = (b * 64 + h0) * 64 + px;
                out[(size_t)pix * 128 + co] = f2bf(gelu_f(acc[ms][ns][rg] + bv));
            }
    }
}

// ---------------------------------------------------------------------------
// 3x3 128->128 conv + GELU via MFMA; halo staged once; weight frags ping-pong
// prefetched one k-group ahead (global->VGPR overlaps the 8 MFMAs).
// GATHER: A-pixels fetched through the packed VQ result (fused codebook
// gather). FUSE: dec2 (1x1 conv 128->16 + sigmoid) fused into the epilogue,
// writing the final NCHW fp32 output.
template <bool OUT_BF16, bool GATHER, bool FUSE>
__global__ __launch_bounds__(256, 2) void conv3x3_mfma_kernel(
    const unsigned short* __restrict__ in,   // NHWC acts, or embbf if GATHER
    const unsigned long long* __restrict__ gidx,  // packed VQ result or null
    const unsigned short* __restrict__ wtb,  // [9][co][ci] bf16
    const float* __restrict__ bias,          // [128]
    const float* __restrict__ w2,            // [16][128] fp32 (FUSE)
    const float* __restrict__ b2,            // [16] fp32 (FUSE)
    void* __restrict__ out_) {               // NHWC bf16/fp32, or NCHW if FUSE
    constexpr int LDC = 136;
    __shared__ __align__(16) unsigned short As[3 * 66 * LDC];  // 53856 B
    __shared__ __align__(16) float ws2[FUSE ? 2048 : 4];
    int tid = threadIdx.x;
    int wv = tid >> 6, lane = tid & 63;
    int r = lane & 15, q = lane >> 4;
    int h0 = blockIdx.x & 63, b = blockIdx.x >> 6;

    constexpr int NJ = FUSE ? 15 : 13;
    for (int j = 0; j < NJ; ++j) {
        int s = tid + j * 256;
        if (s < 3168) {
            int col = s >> 4, chunk = s & 15;
            int ry = col / 66, cx = col % 66;
            int hh = h0 - 1 + ry, ww = cx - 1;
            float4 v = make_float4(0.f, 0.f, 0.f, 0.f);
            if ((unsigned)hh < 64u && (unsigned)ww < 64u) {
                int pix = (b * 64 + hh) * 64 + ww;
                const unsigned short* src;
                if (GATHER) {
                    int k = 8191 - (int)(unsigned)(gidx[pix] & 0xFFFFFFFFu);
                    src = in + (size_t)k * 128;
                } else {
                    src = in + (size_t)pix * 128;
                }
                v = *(const float4*)(src + chunk * 8);
            }
            *(float4*)(As + col * LDC + chunk * 8) = v;
        } else if (FUSE && s < 3680) {
            int i = s - 3168;  // < 512 float4 slots
            ((float4*)ws2)[i] = ((const float4*)w2)[i];
        }
    }
    __syncthreads();

    f32x4 acc[4][2];
#pragma unroll
    for (int ms = 0; ms < 4; ++ms)
#pragma unroll
        for (int ns = 0; ns < 2; ++ns) acc[ms][ns] = (f32x4){0.f, 0.f, 0.f, 0.f};

    // weight ping-pong: groups g = t*4 + k, prefetch g+1 during g's MFMAs
    const unsigned short* wbase = wtb + (wv * 32 + r) * 128 + q * 8;
    short8 bfp[2][2];
    bfp[0][0] = *(const short8*)(wbase);
    bfp[0][1] = *(const short8*)(wbase + 2048);
    int gcur = 0;
    for (int t = 0; t < 9; ++t) {
        int dy = t / 3, dx = t % 3;
#pragma unroll
        for (int k = 0; k < 4; ++k) {
            int cur = gcur & 1, nxt = cur ^ 1;
            if (gcur < 35) {
                int g1 = gcur + 1;
                int t1 = g1 >> 2, k1 = g1 & 3;
                const unsigned short* wp = wbase + t1 * 16384 + k1 * 32;
                bfp[nxt][0] = *(const short8*)(wp);
                bfp[nxt][1] = *(const short8*)(wp + 2048);
            }
            short8 af[4];
#pragma unroll
            for (int ms = 0; ms < 4; ++ms) {
                int col = dy * 66 + ms * 16 + r + dx;
                af[ms] = *(const short8*)(As + col * LDC + k * 32 + q * 8);
            }
#pragma unroll
            for (int ms = 0; ms < 4; ++ms)
#pragma unroll
                for (int ns = 0; ns < 2; ++ns)
                    acc[ms][ns] = __builtin_amdgcn_mfma_f32_16x16x32_bf16(
                        af[ms], bfp[cur][ns], acc[ms][ns], 0, 0, 0);
            ++gcur;
        }
    }

    if (!FUSE) {
#pragma unroll
        for (int ns = 0; ns < 2; ++ns) {
            int co = wv * 32 + ns * 16 + r;
            float bv = bias[co];
#pragma unroll
            for (int ms = 0; ms < 4; ++ms)
#pragma unroll
                for (int rg = 0; rg < 4; ++rg) {
                    int px = ms * 16 + q * 4 + rg;
                    int pix = (b * 64 + h0) * 64 + px;
                    float g = gelu_f(acc[ms][ns][rg] + bv);
                    if (OUT_BF16)
                        ((unsigned short*)out_)[(size_t)pix * 128 + co] = f2bf(g);
                    else
                        ((float*)out_)[(size_t)pix * 128 + co] = g;
                }
        }
    } else {
        // bias+GELU -> LDS (reuse As as float[64][130]), then 1x1+sigmoid
        __syncthreads();  // all af reads done before overwrite
        float* gbuf = (float*)As;
#pragma unroll
        for (int ns = 0; ns < 2; ++ns) {
            int co = wv * 32 + ns * 16 + r;
            float bv = bias[co];
#pragma unroll
            for (int ms = 0; ms < 4; ++ms)
#pragma unroll
                for (int rg = 0; rg < 4; ++rg) {
                    int px = ms * 16 + q * 4 + rg;
                    gbuf[px * 130 + co] = gelu_f(acc[ms][ns][rg] + bv);
                }
        }
        __syncthreads();
        int w_ = tid & 63, c0 = (tid >> 6) * 4;
        float a4[4] = {b2[c0], b2[c0 + 1], b2[c0 + 2], b2[c0 + 3]};
#pragma unroll 1
        for (int ci = 0; ci < 128; ci += 2) {
            float2 yv = *(const float2*)&gbuf[w_ * 130 + ci];
#pragma unroll
            for (int jc = 0; jc < 4; ++jc) {
                float2 wv2 = *(const float2*)&ws2[(c0 + jc) * 128 + ci];
                a4[jc] += yv.x * wv2.x + yv.y * wv2.y;
            }
        }
        float* outp = (float*)out_;
#pragma unroll
        for (int jc = 0; jc < 4; ++jc) {
            float v = 1.0f / (1.0f + expf(-a4[jc]));
            outp[(((size_t)b * 16 + c0 + jc) * 64 + h0) * 64 + w_] = v;
        }
    }
}

// ---------------------------------------------------------------------------
// VQ argmin via bf16 MFMA, K-split x2 (1024 blocks, ~4 blocks/CU at 120 VGPR).
// A resident in LDS; A(LDS)+B(global) frags ping-pong-prefetched one k-group
// ahead. acc init = e2n (= -e2/2, precomputed) -> score = f.e - e2/2, argMAX.
// 10-bit key (it,ns,r) in low mantissa -> v_max_f32 running argmax + in-wave
// shfl merge. Cross-block: atomicMax on (sortable_score<<32 | (8191-code)).
__global__ __launch_bounds__(256, 2) void vq_mfma_kernel(
    const unsigned short* __restrict__ flatbf,  // [N][128] bf16
    const unsigned short* __restrict__ embbf,   // [K][128] bf16
    const float* __restrict__ e2n,              // [K] fp32, -||e||^2/2
    unsigned long long* __restrict__ partial) { // [N] packed, zero-inited
    constexpr int LDA = 136;
    __shared__ __align__(16) unsigned short As[64 * LDA];   // 17408 B
    __shared__ unsigned long long merged[64][4];            // 2048 B
    int tid = threadIdx.x;
    int wv = tid >> 6, lane = tid & 63;
    int r = lane & 15, q = lane >> 4;
    int half = blockIdx.x & 1;
    int m0 = (blockIdx.x >> 1) * 64;
    int kbase = half * 4096;

    // stage A (64 px x 128 d); stays resident in LDS for the whole kernel
#pragma unroll
    for (int j = 0; j < 4; ++j) {
        int row = j * 16 + (tid >> 4), col = tid & 15;
        float4 v = *(const float4*)(flatbf + (size_t)(m0 + row) * 128 + col * 8);
        *(float4*)(As + row * LDA + col * 8) = v;
    }
    __syncthreads();

    const unsigned short* bp =
        embbf + (size_t)(kbase + wv * 64 + r) * 128 + q * 8;
    const float* e2p = e2n + kbase + wv * 64 + r;

    float best[4][4];
#pragma unroll
    for (int ms = 0; ms < 4; ++ms)
#pragma unroll
        for (int rg = 0; rg < 4; ++rg) best[ms][rg] = -3.4e38f;

    short8 af[2][4], bf[2][4];
    float e2v[4];
    // prologue: group 0 frags + e2n for it=0
#pragma unroll
    for (int ms = 0; ms < 4; ++ms)
        af[0][ms] = *(const short8*)(As + (ms * 16 + r) * LDA + q * 8);
#pragma unroll
    for (int ns = 0; ns < 4; ++ns) bf[0][ns] = *(const short8*)(bp + ns * 2048);
#pragma unroll
    for (int ns = 0; ns < 4; ++ns) e2v[ns] = e2p[ns * 16];

    f32x4 acc[4][4];
#pragma unroll
    for (int ns = 0; ns < 4; ++ns) {
        float v = e2v[ns];
#pragma unroll
        for (int ms = 0; ms < 4; ++ms) acc[ms][ns] = (f32x4){v, v, v, v};
    }

    int key0 = 1023 - r;
#pragma unroll 4
    for (int g = 0; g < 64; ++g) {
        int cur = g & 1, nxt = cur ^ 1;
        int it = g >> 2, kk = g & 3;
        if (g < 63) {  // prefetch group g+1 (A from LDS, B from L2)
            int it1 = (g + 1) >> 2, kk1 = (g + 1) & 3;
#pragma unroll
            for (int ms = 0; ms < 4; ++ms)
                af[nxt][ms] = *(const short8*)(As + (ms * 16 + r) * LDA +
                                               kk1 * 32 + q * 8);
#pragma unroll
            for (int ns = 0; ns < 4; ++ns)
                bf[nxt][ns] = *(const short8*)(bp + (size_t)it1 * 32768 +
                                               ns * 2048 + kk1 * 32);
        }
        if (kk == 2 && it < 15) {  // e2n for next iter (consumed at reinit)
#pragma unroll
            for (int ns = 0; ns < 4; ++ns)
                e2v[ns] = e2p[(it + 1) * 256 + ns * 16];
        }
#pragma unroll
        for (int ms = 0; ms < 4; ++ms)
#pragma unroll
            for (int ns = 0; ns < 4; ++ns)
                acc[ms][ns] = __builtin_amdgcn_mfma_f32_16x16x32_bf16(
                    af[cur][ms], bf[cur][ns], acc[ms][ns], 0, 0, 0);
        if (kk == 3) {
            // epilogue: pack 10-bit key, running max
#pragma unroll
            for (int ns = 0; ns < 4; ++ns) {
                unsigned keyv = (unsigned)(key0 - (it * 64 + ns * 16));
#pragma unroll
                for (int ms = 0; ms < 4; ++ms)
#pragma unroll
                    for (int rg = 0; rg < 4; ++rg) {
                        unsigned u =
                            (__float_as_uint(acc[ms][ns][rg]) & 0xFFFFFC00u) |
                            keyv;
                        best[ms][rg] = fmaxf(best[ms][rg], __uint_as_float(u));
                    }
            }
            if (it < 15) {  // reinit acc for next iter
#pragma unroll
                for (int ns = 0; ns < 4; ++ns) {
                    float v = e2v[ns];
#pragma unroll
                    for (int ms = 0; ms < 4; ++ms)
                        acc[ms][ns] = (f32x4){v, v, v, v};
                }
            }
        }
    }

    // in-wave merge over the 16 r-lanes (key encodes it,ns,r -> recoverable)
#pragma unroll
    for (int ms = 0; ms < 4; ++ms)
#pragma unroll
        for (int rg = 0; rg < 4; ++rg) {
            float v = best[ms][rg];
#pragma unroll
            for (int m = 1; m < 16; m <<= 1)
                v = fmaxf(v, __shfl_xor(v, m));
            best[ms][rg] = v;
        }
    if (r == 0) {
#pragma unroll
        for (int ms = 0; ms < 4; ++ms)
#pragma unroll
            for (int rg = 0; rg < 4; ++rg) {
                unsigned bits = __float_as_uint(best[ms][rg]);
                int cand = 1023 - (int)(bits & 1023u);
                int code = kbase + wv * 64 + (cand >> 6) * 256 +
                           ((cand >> 4) & 3) * 16 + (cand & 15);
                unsigned sb =
                    (bits & 0x80000000u) ? ~bits : (bits | 0x80000000u);
                unsigned long long packed =
                    ((unsigned long long)sb << 32) | (unsigned)(8191 - code);
                merged[ms * 16 + q * 4 + rg][wv] = packed;
            }
    }
    __syncthreads();
    if (tid < 64) {
        unsigned long long bp0 = merged[tid][0];
        bp0 = bp0 > merged[tid][1] ? bp0 : merged[tid][1];
        bp0 = bp0 > merged[tid][2] ? bp0 : merged[tid][2];
        bp0 = bp0 > merged[tid][3] ? bp0 : merged[tid][3];
        atomicMax(partial + m0 + tid, bp0);
    }
}

// ---------------------------------------------------------------------------
extern "C" void kernel_launch(void* const* d_in, const int* in_sizes, int n_in,
                              void* d_out, int out_size, void* d_ws,
                              size_t ws_size, hipStream_t stream) {
    const float* x = (const float*)d_in[0];
    const float* ew1 = (const float*)d_in[1];
    const float* eb1 = (const float*)d_in[2];
    const float* ew2 = (const float*)d_in[3];
    const float* eb2 = (const float*)d_in[4];
    const float* embed = (const float*)d_in[5];
    const float* dw1 = (const float*)d_in[6];
    const float* db1 = (const float*)d_in[7];
    const float* dw2 = (const float*)d_in[8];
    const float* db2 = (const float*)d_in[9];
    float* out = (float*)d_out;

    float* e2n = (float*)d_ws;                             // 8192 f
    unsigned long long* partial =
        (unsigned long long*)(e2n + 8192);                 // 32768 u64
    unsigned short* xtbf = (unsigned short*)(partial + 32768);  // 524288 us
    unsigned short* wtb1b = xtbf + 524288;                 // 20480 us
    unsigned short* wtbf2 = wtb1b + 20480;                 // 147456 us
    unsigned short* wtbf3 = wtbf2 + 147456;                // 147456 us
    unsigned short* embbf = wtbf3 + 147456;                // 1048576 us
    unsigned short* abf = embbf + 1048576;                 // 4194304 us
    unsigned short* flatbf = abf + 4194304;                // 4194304 us

    prep_kernel<<<4464, 256, 0, stream>>>(x, ew1, ew2, dw1, embed, xtbf, wtbf2,
                                          wtbf3, e2n, embbf, wtb1b, partial);
    conv1_mfma_kernel<<<512, 256, 0, stream>>>(xtbf, wtb1b, eb1, abf);
    conv3x3_mfma_kernel<true, false, false><<<512, 256, 0, stream>>>(
        abf, nullptr, wtbf2, eb2, nullptr, nullptr, flatbf);
    vq_mfma_kernel<<<1024, 256, 0, stream>>>(flatbf, embbf, e2n, partial);
    conv3x3_mfma_kernel<false, true, true><<<512, 256, 0, stream>>>(
        embbf, partial, wtbf3, db1, dw2, db2, out);
}